// Round 4
// baseline (208.942 us; speedup 1.0000x reference)
//
#include <hip/hip_runtime.h>
#include <hip/hip_bf16.h>

// MultiHeadAttention, raw-reshape semantics: head (b,h) = contiguous flat block
// [(b*8+h)*98304 : +98304] of the (B,N,E) projection viewed as (1024 x 96).
// Pipeline: fused casts; fused QKV gemm (128x256 tile, BK=64, serial 2-barrier
// loop, XOR-swizzled global_load_lds staging, 32x32x16 MFMA); kappa-permuted V
// transpose; S^T flash attention (32x32 MFMA, fixed-max softmax); proj gemm
// (128x128, same structure).
//
// R4: R3's coarse pipeline regressed (m196's warned case: counted-vmcnt w/o
// fine interleave, 1 block/CU, 576-block grid at 1-residency). Reverted to the
// proven serial 2-barrier loop; improved geometry instead: gemm_qkv 128x256
// with 4 waves (wave out 64x128, acc[2][4]) -> 6 ds_read : 8 MFMA per ks
// (was 1:1), 32 MFMA per barrier phase (was 16), A-panel re-reads halved.
// gemm_proj upgraded 64x128 -> 128x128 (exact proven qkv structure).

typedef __attribute__((ext_vector_type(8))) short short8;
typedef __attribute__((ext_vector_type(4))) float floatx4;
typedef __attribute__((ext_vector_type(16))) float floatx16;

static constexpr int EMB = 768;
static constexpr int SEQ = 1024;
static constexpr int DH = 96;
static constexpr int NBH = 64;
static constexpr int HEADBLK = SEQ * DH;
static constexpr int MROWS = 8192;
static constexpr int NW = EMB * EMB;       // 589824
static constexpr int QKVN = 3 * EMB;       // 2304

// fast RNE f32->bf16 (no NaN path — all values here are finite)
__device__ __forceinline__ unsigned bfround(float f) {
    unsigned u = __builtin_bit_cast(unsigned, f);
    return u + 0x7FFFu + ((u >> 16) & 1u);
}
__device__ __forceinline__ unsigned short f2bf(float f) {
    return (unsigned short)(bfround(f) >> 16);
}
__device__ __forceinline__ unsigned pk2(float lo, float hi) {
    return (bfround(lo) >> 16) | (bfround(hi) & 0xFFFF0000u);
}

__device__ __forceinline__ void gload16(const unsigned short* g, unsigned short* l) {
    __builtin_amdgcn_global_load_lds(
        (const __attribute__((address_space(1))) unsigned int*)g,
        (__attribute__((address_space(3))) unsigned int*)l, 16, 0, 0);
}

// ---------------- fused casts: x (6144 blk) | weights (2304 blk) | bias (9 blk) ----------------
__global__ void cast_all(const float* __restrict__ x,
                         const float* __restrict__ Wq, const float* __restrict__ Wk,
                         const float* __restrict__ Wv, const float* __restrict__ Wp,
                         const float* __restrict__ bq, const float* __restrict__ bk,
                         const float* __restrict__ bv,
                         unsigned short* __restrict__ xb,
                         unsigned short* __restrict__ Wqkv, unsigned short* __restrict__ Wpb,
                         float* __restrict__ bias) {
    int bx = blockIdx.x;
    if (bx < 6144) {
        int i = bx * 1024 + threadIdx.x * 4;
        float4 v = *reinterpret_cast<const float4*>(x + i);
        ushort4 o;
        o.x = f2bf(v.x); o.y = f2bf(v.y); o.z = f2bf(v.z); o.w = f2bf(v.w);
        *reinterpret_cast<ushort4*>(xb + i) = o;
    } else if (bx < 8448) {
        int i4 = (bx - 6144) * 1024 + threadIdx.x * 4;
        const float* src;
        unsigned short* dst;
        if (i4 < 3 * NW) {
            int wi = i4 / NW;
            src = (wi == 0) ? Wq + i4 : (wi == 1) ? Wk + (i4 - NW) : Wv + (i4 - 2 * NW);
            dst = Wqkv + i4;
        } else {
            src = Wp + (i4 - 3 * NW);
            dst = Wpb + (i4 - 3 * NW);
        }
        float4 v = *reinterpret_cast<const float4*>(src);
        ushort4 o;
        o.x = f2bf(v.x); o.y = f2bf(v.y); o.z = f2bf(v.z); o.w = f2bf(v.w);
        *reinterpret_cast<ushort4*>(dst) = o;
    } else {
        int j = (bx - 8448) * 256 + threadIdx.x;
        if (j < QKVN)
            bias[j] = (j < 768) ? bq[j] : (j < 1536) ? bk[j - 768] : bv[j - 1536];
    }
}

// ---------------- fused QKV GEMM (128x256 tile, BK=64, 32x32x16 MFMA) ----------------
// C[m,n] = sum_k x[m,k]*Wqkv[n,k] + bias[n]; by: 0-2 -> Q, 3-5 -> K, 6-8 -> V.
// Staging swizzle (pre-swizzled global source, linear LDS dest): LDS row r
// chunk-slot cc holds global k-chunk cc^(r&7); fragment reads apply same XOR.
// 32x32x16 frags (m74/m101): A m=lane&31, k=(lane>>5)*8+j;
// C/D col=lane&31, row=(reg&3)+8*(reg>>2)+4*(lane>>5).
// 4 waves, wave output 64x128 (acc[2][4]): per ks, 2 A + 4 B ds_read_b128 feed
// 8 MFMA (ratio 0.75 vs R2's 1.0); 32 MFMA per barrier phase.
__global__ __launch_bounds__(256) void gemm_qkv(
    const unsigned short* __restrict__ A,    // 8192 x 768
    const unsigned short* __restrict__ Bm,   // 2304 x 768
    const float* __restrict__ bias,
    unsigned short* __restrict__ Qo,
    unsigned short* __restrict__ Ko,
    unsigned short* __restrict__ Vo) {
    __shared__ unsigned short As[128 * 64];   // 16 KB
    __shared__ unsigned short Bs[256 * 64];   // 32 KB
    const int K = EMB;

    const int t = threadIdx.x;
    const int lane = t & 63;
    const int w = t >> 6;            // 0..3
    const int wm = (w >> 1) * 64;    // 0,64
    const int wn = (w & 1) * 128;    // 0,128
    const int l32 = lane & 31;
    const int lh = lane >> 5;
    const int sx = lane & 7;
    const int bm = blockIdx.x * 128;
    const int by = blockIdx.y;
    const int bn = by * 256;

    const unsigned short* Agp[4];
    const unsigned short* Bgp[8];
#pragma unroll
    for (int i = 0; i < 4; i++) {
        int f = i * 2048 + w * 512 + lane * 8;
        int row = f >> 6;
        int cc = (f >> 3) & 7;
        Agp[i] = A + (size_t)(bm + row) * K + ((cc ^ (row & 7)) * 8);
    }
#pragma unroll
    for (int i = 0; i < 8; i++) {
        int f = i * 2048 + w * 512 + lane * 8;
        int row = f >> 6;
        int cc = (f >> 3) & 7;
        Bgp[i] = Bm + (size_t)(bn + row) * K + ((cc ^ (row & 7)) * 8);
    }

    floatx16 acc[2][4];
#pragma unroll
    for (int i = 0; i < 2; i++)
#pragma unroll
        for (int j = 0; j < 4; j++)
#pragma unroll
            for (int r = 0; r < 16; r++) acc[i][j][r] = 0.0f;

    for (int k0 = 0; k0 < K; k0 += 64) {
        __syncthreads();
#pragma unroll
        for (int i = 0; i < 4; i++)
            gload16(Agp[i] + k0, As + i * 2048 + w * 512);
#pragma unroll
        for (int i = 0; i < 8; i++)
            gload16(Bgp[i] + k0, Bs + i * 2048 + w * 512);
        __syncthreads();

#pragma unroll
        for (int ks = 0; ks < 4; ks++) {
            const int co = ((ks * 2 + lh) ^ sx) * 8;
            short8 af[2], bfq[4];
#pragma unroll
            for (int mt = 0; mt < 2; mt++)
                af[mt] = *reinterpret_cast<const short8*>(As + (wm + mt * 32 + l32) * 64 + co);
#pragma unroll
            for (int nt = 0; nt < 4; nt++)
                bfq[nt] = *reinterpret_cast<const short8*>(Bs + (wn + nt * 32 + l32) * 64 + co);
#pragma unroll
            for (int mt = 0; mt < 2; mt++)
#pragma unroll
                for (int nt = 0; nt < 4; nt++)
                    acc[mt][nt] = __builtin_amdgcn_mfma_f32_32x32x16_bf16(
                        af[mt], bfq[nt], acc[mt][nt], 0, 0, 0);
        }
    }

    unsigned short* dst = (by < 3) ? Qo : (by < 6) ? Ko : Vo;
    const int bnl = (by % 3) * 256;
#pragma unroll
    for (int mt = 0; mt < 2; mt++) {
#pragma unroll
        for (int nt = 0; nt < 4; nt++) {
            int colg = bn + wn + nt * 32 + l32;
            int coll = bnl + wn + nt * 32 + l32;
            float bb = bias[colg];
#pragma unroll
            for (int rg = 0; rg < 4; rg++) {
                int rowb = bm + wm + mt * 32 + rg * 8 + lh * 4;
#pragma unroll
                for (int rr = 0; rr < 4; rr++)
                    dst[(size_t)(rowb + rr) * EMB + coll] = f2bf(acc[mt][nt][rg * 4 + rr] + bb);
            }
        }
    }
}

// ---------------- proj GEMM (128x128 tile, BK=64, 32x32x16 MFMA; grid 64x6) ----------------
__global__ __launch_bounds__(256) void gemm_proj(
    const unsigned short* __restrict__ A,
    const unsigned short* __restrict__ Bm,
    const float* __restrict__ bias,
    float* __restrict__ C) {
    __shared__ unsigned short As[128 * 64];
    __shared__ unsigned short Bs[128 * 64];
    const int K = EMB, N = EMB;

    const int t = threadIdx.x;
    const int lane = t & 63;
    const int w = t >> 6;
    const int wm = (w >> 1) * 64;
    const int wn = (w & 1) * 64;
    const int l32 = lane & 31;
    const int lh = lane >> 5;
    const int sx = lane & 7;
    const int bm = blockIdx.x * 128;
    const int bn = blockIdx.y * 128;

    const unsigned short* Agp[4];
    const unsigned short* Bgp[4];
#pragma unroll
    for (int i = 0; i < 4; i++) {
        int f = i * 2048 + w * 512 + lane * 8;
        int row = f >> 6;
        int cc = (f >> 3) & 7;
        Agp[i] = A + (size_t)(bm + row) * K + ((cc ^ (row & 7)) * 8);
        Bgp[i] = Bm + (size_t)(bn + row) * K + ((cc ^ (row & 7)) * 8);
    }

    floatx16 acc[2][2];
#pragma unroll
    for (int i = 0; i < 2; i++)
#pragma unroll
        for (int j = 0; j < 2; j++)
#pragma unroll
            for (int r = 0; r < 16; r++) acc[i][j][r] = 0.0f;

    for (int k0 = 0; k0 < K; k0 += 64) {
        __syncthreads();
#pragma unroll
        for (int i = 0; i < 4; i++) {
            gload16(Agp[i] + k0, As + i * 2048 + w * 512);
            gload16(Bgp[i] + k0, Bs + i * 2048 + w * 512);
        }
        __syncthreads();

#pragma unroll
        for (int ks = 0; ks < 4; ks++) {
            const int co = ((ks * 2 + lh) ^ sx) * 8;
            short8 af[2], bfr[2];
#pragma unroll
            for (int mt = 0; mt < 2; mt++)
                af[mt] = *reinterpret_cast<const short8*>(As + (wm + mt * 32 + l32) * 64 + co);
#pragma unroll
            for (int nt = 0; nt < 2; nt++)
                bfr[nt] = *reinterpret_cast<const short8*>(Bs + (wn + nt * 32 + l32) * 64 + co);
#pragma unroll
            for (int mt = 0; mt < 2; mt++)
#pragma unroll
                for (int nt = 0; nt < 2; nt++)
                    acc[mt][nt] = __builtin_amdgcn_mfma_f32_32x32x16_bf16(
                        af[mt], bfr[nt], acc[mt][nt], 0, 0, 0);
        }
    }

#pragma unroll
    for (int mt = 0; mt < 2; mt++) {
#pragma unroll
        for (int nt = 0; nt < 2; nt++) {
            int col = bn + wn + nt * 32 + l32;
            float bb = bias[col];
#pragma unroll
            for (int rg = 0; rg < 4; rg++) {
                int rowb = bm + wm + mt * 32 + rg * 8 + lh * 4;
#pragma unroll
                for (int rr = 0; rr < 4; rr++)
                    C[(size_t)(rowb + rr) * N + col] = acc[mt][nt][rg * 4 + rr] + bb;
            }
        }
    }
}

// ---------------- V transpose with kappa key-permutation (flat head blocks) ----------------
// Vt[bh][d][blk*64 + p] = V[bh][blk*64 + kappa(p)][d],
// kappa(p) = (p & ~12) | ((p&4)<<1) | ((p&8)>>1)   (swap key-quads 1<->2 per 16)
// so the attn PV B-fragment packs linearly from sacc (reg r = j + 8*(kt2&1)).
__global__ __launch_bounds__(256) void transpose_v(const unsigned short* __restrict__ V,
                                                   unsigned short* __restrict__ Vt) {
    __shared__ unsigned short L[64 * 104];
    const int t = threadIdx.x;
    const int bh = blockIdx.x, nb = blockIdx.y;
    const unsigned short* Vg = V + (size_t)bh * HEADBLK + (size_t)nb * 64 * DH;
#pragma unroll
    for (int i = 0; i < 3; i++) {
        int f = i * 2048 + t * 8;
        int r = f / 96, c = f - r * 96;
        *reinterpret_cast<short8*>(L + r * 104 + c) = *reinterpret_cast<const short8*>(Vg + f);
    }
    __syncthreads();
    unsigned short* dst = Vt + (size_t)bh * HEADBLK;
#pragma unroll
    for (int i = 0; i < 3; i++) {
        int f = i * 2048 + t * 8;
        int d = f >> 6, c0 = f & 63;
        union { short8 s; unsigned short u[8]; } o;
#pragma unroll
        for (int j = 0; j < 8; j++) {
            int c = c0 + j;
            int key = (c & ~12) | ((c & 4) << 1) | ((c & 8) >> 1);
            o.u[j] = L[key * 104 + d];
        }
        *reinterpret_cast<short8*>(dst + d * SEQ + nb * 64 + c0) = o.s;
    }
}

// ---------------- flash attention, S^T form, 32x32x16 MFMA ----------------
// grid (64 heads, 8 qb): flat id = bh + 64*qb -> XCD = bh%8 (all q-blocks of a
// head share one XCD's L2). Block = 128 q rows, wave owns 32 q (l32 = q).
// S^T = K*Q per 64-key tile: A = K (m=key), B = Q regs (n=q), sacc[kt] col=q,
// row=key=(r&3)+8*(r>>2)+4*lh. m=0 softmax (|S|<~18 bounded): exp in place,
// row-sum = 31 adds + 1 shfl_xor(32). PV: A = kappa-permuted Vt (m=d), B = P
// packed from sacc regs r = j + 8*(kt2&1).
__global__ __launch_bounds__(256, 2) void attn_kernel(
    const unsigned short* __restrict__ Q,
    const unsigned short* __restrict__ K,
    const unsigned short* __restrict__ Vt,   // per head: 96 x 1024, keys kappa-permuted per 16
    unsigned short* __restrict__ O) {
    __shared__ unsigned short Ks[64 * 104];
    __shared__ unsigned short Vs[96 * 72];

    const int t = threadIdx.x;
    const int lane = t & 63;
    const int w = t >> 6;
    const int l32 = lane & 31;
    const int lh = lane >> 5;
    const int bh = blockIdx.x, qb = blockIdx.y;

    const unsigned short* Qh = Q + (size_t)bh * HEADBLK;
    const unsigned short* Kh = K + (size_t)bh * HEADBLK;
    const unsigned short* Vth = Vt + (size_t)bh * HEADBLK;

    // Q B-fragments (32x32x16): n = l32 = q row, k = lh*8+j, ks = 0..5 chunks of 16.
    short8 qf[6];
    {
        const unsigned short* qsrc = Qh + (size_t)(qb * 128 + w * 32 + l32) * DH + lh * 8;
#pragma unroll
        for (int ks = 0; ks < 6; ks++)
            qf[ks] = *reinterpret_cast<const short8*>(qsrc + ks * 16);
    }

    const unsigned short* Kp[3];
    const unsigned short* Vp[3];
    unsigned short* KsW[3];
    unsigned short* VsW[3];
#pragma unroll
    for (int i = 0; i < 3; i++) {
        int f = i * 2048 + t * 8;
        int r = f / 96, c = f - r * 96;
        Kp[i] = Kh + f;              // + kb*6144
        KsW[i] = Ks + r * 104 + c;
        int d = f >> 6, cv = f & 63;
        Vp[i] = Vth + d * SEQ + cv;  // + kb*64
        VsW[i] = Vs + d * 72 + cv;
    }

    short8 kreg[3], vreg[3];
#pragma unroll
    for (int i = 0; i < 3; i++) {
        kreg[i] = *reinterpret_cast<const short8*>(Kp[i]);
        vreg[i] = *reinterpret_cast<const short8*>(Vp[i]);
    }

    float l_ = 0.0f;
    floatx16 acco[3];
#pragma unroll
    for (int n = 0; n < 3; n++)
#pragma unroll
        for (int r = 0; r < 16; r++) acco[n][r] = 0.0f;

    for (int kb = 0; kb < 16; kb++) {
        __syncthreads();
#pragma unroll
        for (int i = 0; i < 3; i++) {
            *reinterpret_cast<short8*>(KsW[i]) = kreg[i];
            *reinterpret_cast<short8*>(VsW[i]) = vreg[i];
        }
        __syncthreads();
        if (kb < 15) {
#pragma unroll
            for (int i = 0; i < 3; i++) {
                kreg[i] = *reinterpret_cast<const short8*>(Kp[i] + (kb + 1) * 6144);
                vreg[i] = *reinterpret_cast<const short8*>(Vp[i] + (kb + 1) * 64);
            }
        }

        floatx16 sacc[2];
#pragma unroll
        for (int kt = 0; kt < 2; kt++)
#pragma unroll
            for (int r = 0; r < 16; r++) sacc[kt][r] = 0.0f;

#pragma unroll
        for (int ks = 0; ks < 6; ks++) {
#pragma unroll
            for (int kt = 0; kt < 2; kt++) {
                short8 ak = *reinterpret_cast<const short8*>(
                    Ks + (kt * 32 + l32) * 104 + ks * 16 + lh * 8);
                sacc[kt] = __builtin_amdgcn_mfma_f32_32x32x16_bf16(ak, qf[ks], sacc[kt], 0, 0, 0);
            }
        }

        // exp in place; row-sum (lane holds 32 keys of one q; partner lane ^32
        // holds the other 32 keys of the same q)
        float rs = 0.0f;
#pragma unroll
        for (int kt = 0; kt < 2; kt++)
#pragma unroll
            for (int r = 0; r < 16; r++) {
                float v = __expf(sacc[kt][r]);
                sacc[kt][r] = v;
                rs += v;
            }
        rs += __shfl_xor(rs, 32);
        l_ += rs;

#pragma unroll
        for (int kt2 = 0; kt2 < 4; kt2++) {
            const int kt = kt2 >> 1, ro = (kt2 & 1) * 8;
            union { short8 s8; unsigned u[4]; } bp;
#pragma unroll
            for (int p = 0; p < 4; p++)
                bp.u[p] = pk2(sacc[kt][ro + 2 * p], sacc[kt][ro + 2 * p + 1]);
#pragma unroll
            for (int n = 0; n < 3; n++) {
                short8 av = *reinterpret_cast<const short8*>(
                    Vs + (n * 32 + l32) * 72 + kt2 * 16 + lh * 8);
                acco[n] = __builtin_amdgcn_mfma_f32_32x32x16_bf16(av, bp.s8, acco[n], 0, 0, 0);
            }
        }
    }

    const float inv_sqrt_e = 0.036084391824351615f;
    float invl = inv_sqrt_e / l_;
    unsigned short* dst = O + (size_t)bh * HEADBLK +
                          (size_t)(qb * 128 + w * 32 + l32) * DH + lh * 4;
#pragma unroll
    for (int n = 0; n < 3; n++) {
#pragma unroll
        for (int rg = 0; rg < 4; rg++) {
            uint2 o2;
            o2.x = pk2(acco[n][rg * 4 + 0] * invl, acco[n][rg * 4 + 1] * invl);
            o2.y = pk2(acco[n][rg * 4 + 2] * invl, acco[n][rg * 4 + 3] * invl);
            *reinterpret_cast<uint2*>(dst + n * 32 + rg * 8) = o2;
        }
    }
}

extern "C" void kernel_launch(void* const* d_in, const int* in_sizes, int n_in,
                              void* d_out, int out_size, void* d_ws, size_t ws_size,
                              hipStream_t stream) {
    const float* x = (const float*)d_in[0];
    const float* Wq = (const float*)d_in[1];
    const float* bq = (const float*)d_in[2];
    const float* Wk = (const float*)d_in[3];
    const float* bk = (const float*)d_in[4];
    const float* Wv = (const float*)d_in[5];
    const float* bv = (const float*)d_in[6];
    const float* Wp = (const float*)d_in[7];
    const float* bp = (const float*)d_in[8];
    float* out = (float*)d_out;

    char* ws = (char*)d_ws;
    size_t off = 0;
    auto alloc = [&](size_t bytes) {
        char* p = ws + off;
        off += (bytes + 255) & ~(size_t)255;
        return p;
    };
    const int nx = MROWS * EMB;
    unsigned short* xb    = (unsigned short*)alloc((size_t)nx * 2);
    unsigned short* Wqkvb = (unsigned short*)alloc((size_t)3 * NW * 2);
    unsigned short* Wpb   = (unsigned short*)alloc((size_t)NW * 2);
    float*          biasq = (float*)alloc((size_t)QKVN * 4);
    unsigned short* Qb    = (unsigned short*)alloc((size_t)nx * 2);
    unsigned short* Kb    = (unsigned short*)alloc((size_t)nx * 2);
    unsigned short* Vb    = (unsigned short*)alloc((size_t)nx * 2);
    unsigned short* Vtb   = (unsigned short*)alloc((size_t)nx * 2);
    unsigned short* Ob    = (unsigned short*)alloc((size_t)nx * 2);

    cast_all<<<8457, 256, 0, stream>>>(x, Wq, Wk, Wv, Wp, bq, bk, bv,
                                       xb, Wqkvb, Wpb, biasq);

    gemm_qkv<<<dim3(MROWS / 128, QKVN / 256), 256, 0, stream>>>(
        xb, Wqkvb, biasq, Qb, Kb, Vb);

    transpose_v<<<dim3(NBH, SEQ / 64), 256, 0, stream>>>(Vb, Vtb);

    attn_kernel<<<dim3(NBH, SEQ / 128), 256, 0, stream>>>(Qb, Kb, Vtb, Ob);

    gemm_proj<<<dim3(MROWS / 128, EMB / 128), 256, 0, stream>>>(Ob, Wpb, bp, out);
}

// Round 5
// 188.264 us; speedup vs baseline: 1.1098x; 1.1098x over previous
//
#include <hip/hip_runtime.h>
#include <hip/hip_bf16.h>

// MultiHeadAttention, raw-reshape semantics: head (b,h) = contiguous flat block
// [(b*8+h)*98304 : +98304] of the (B,N,E) projection viewed as (1024 x 96).
// Pipeline: fused casts; fused QKV gemm (128x128, BK=64, XOR-swizzled
// global_load_lds staging, 32x32x16 MFMA); kappa-permuted V transpose; S^T
// flash attention (32x32 MFMA, fixed-max softmax, double-buffered K/V LDS);
// proj gemm (64x128, BK=64, 32x32x16 MFMA).
//
// R5: R3 (coarse pipeline) and R4 (fat tile) both regressed gemm_qkv ->
// reverted to the exact R2 GEMMs (674 TF local optimum for K=768).
// Attn change only: double-buffer Ks/Vs (27->53KB) = ONE barrier per kb-tile
// (was 2), raw s_barrier + explicit lgkmcnt(0) (no vmcnt drain), and next
// tile's global loads issued BEFORE the barrier so HBM/L2 latency overlaps
// barrier wait + compute.

typedef __attribute__((ext_vector_type(8))) short short8;
typedef __attribute__((ext_vector_type(4))) float floatx4;
typedef __attribute__((ext_vector_type(16))) float floatx16;

static constexpr int EMB = 768;
static constexpr int SEQ = 1024;
static constexpr int DH = 96;
static constexpr int NBH = 64;
static constexpr int HEADBLK = SEQ * DH;
static constexpr int MROWS = 8192;
static constexpr int NW = EMB * EMB;       // 589824
static constexpr int QKVN = 3 * EMB;       // 2304

// fast RNE f32->bf16 (no NaN path — all values here are finite)
__device__ __forceinline__ unsigned bfround(float f) {
    unsigned u = __builtin_bit_cast(unsigned, f);
    return u + 0x7FFFu + ((u >> 16) & 1u);
}
__device__ __forceinline__ unsigned short f2bf(float f) {
    return (unsigned short)(bfround(f) >> 16);
}
__device__ __forceinline__ unsigned pk2(float lo, float hi) {
    return (bfround(lo) >> 16) | (bfround(hi) & 0xFFFF0000u);
}

__device__ __forceinline__ void gload16(const unsigned short* g, unsigned short* l) {
    __builtin_amdgcn_global_load_lds(
        (const __attribute__((address_space(1))) unsigned int*)g,
        (__attribute__((address_space(3))) unsigned int*)l, 16, 0, 0);
}

// ---------------- fused casts: x (6144 blk) | weights (2304 blk) | bias (9 blk) ----------------
__global__ void cast_all(const float* __restrict__ x,
                         const float* __restrict__ Wq, const float* __restrict__ Wk,
                         const float* __restrict__ Wv, const float* __restrict__ Wp,
                         const float* __restrict__ bq, const float* __restrict__ bk,
                         const float* __restrict__ bv,
                         unsigned short* __restrict__ xb,
                         unsigned short* __restrict__ Wqkv, unsigned short* __restrict__ Wpb,
                         float* __restrict__ bias) {
    int bx = blockIdx.x;
    if (bx < 6144) {
        int i = bx * 1024 + threadIdx.x * 4;
        float4 v = *reinterpret_cast<const float4*>(x + i);
        ushort4 o;
        o.x = f2bf(v.x); o.y = f2bf(v.y); o.z = f2bf(v.z); o.w = f2bf(v.w);
        *reinterpret_cast<ushort4*>(xb + i) = o;
    } else if (bx < 8448) {
        int i4 = (bx - 6144) * 1024 + threadIdx.x * 4;
        const float* src;
        unsigned short* dst;
        if (i4 < 3 * NW) {
            int wi = i4 / NW;
            src = (wi == 0) ? Wq + i4 : (wi == 1) ? Wk + (i4 - NW) : Wv + (i4 - 2 * NW);
            dst = Wqkv + i4;
        } else {
            src = Wp + (i4 - 3 * NW);
            dst = Wpb + (i4 - 3 * NW);
        }
        float4 v = *reinterpret_cast<const float4*>(src);
        ushort4 o;
        o.x = f2bf(v.x); o.y = f2bf(v.y); o.z = f2bf(v.z); o.w = f2bf(v.w);
        *reinterpret_cast<ushort4*>(dst) = o;
    } else {
        int j = (bx - 8448) * 256 + threadIdx.x;
        if (j < QKVN)
            bias[j] = (j < 768) ? bq[j] : (j < 1536) ? bk[j - 768] : bv[j - 1536];
    }
}

// ---------------- fused QKV GEMM (128x128 tile, BK=64, 32x32x16 MFMA) ----------------
// C[m,n] = sum_k x[m,k]*Wqkv[n,k] + bias[n]; by/6 selects Q/K/V output buffer.
// Staging swizzle (conflicts=0): LDS row r chunk-slot cc holds global
// k-chunk cc^(r&7); fragment reads apply the same XOR.
// 32x32x16 frags (m74/m101 verified): A m=lane&31, k=(lane>>5)*8+j;
// C/D col=lane&31, row=(reg&3)+8*(reg>>2)+4*(lane>>5).
__global__ __launch_bounds__(256) void gemm_qkv(
    const unsigned short* __restrict__ A,    // 8192 x 768
    const unsigned short* __restrict__ Bm,   // 2304 x 768
    const float* __restrict__ bias,
    unsigned short* __restrict__ Qo,
    unsigned short* __restrict__ Ko,
    unsigned short* __restrict__ Vo) {
    __shared__ unsigned short As[128 * 64];
    __shared__ unsigned short Bs[128 * 64];
    const int K = EMB;

    const int t = threadIdx.x;
    const int lane = t & 63;
    const int w = t >> 6;
    const int wm = (w >> 1) * 64;
    const int wn = (w & 1) * 64;
    const int l32 = lane & 31;
    const int lh = lane >> 5;
    const int bm = blockIdx.x * 128;
    const int by = blockIdx.y;
    const int bn = by * 128;

    const unsigned short* Agp[4];
    const unsigned short* Bgp[4];
#pragma unroll
    for (int i = 0; i < 4; i++) {
        int f = i * 2048 + w * 512 + lane * 8;
        int row = f >> 6;
        int cc = (f >> 3) & 7;
        int gk = (cc ^ (row & 7)) * 8;
        Agp[i] = A + (size_t)(bm + row) * K + gk;
        Bgp[i] = Bm + (size_t)(bn + row) * K + gk;
    }

    floatx16 acc[2][2];
#pragma unroll
    for (int i = 0; i < 2; i++)
#pragma unroll
        for (int j = 0; j < 2; j++)
#pragma unroll
            for (int r = 0; r < 16; r++) acc[i][j][r] = 0.0f;

    const int sx = lane & 7;
    for (int k0 = 0; k0 < K; k0 += 64) {
        __syncthreads();
#pragma unroll
        for (int i = 0; i < 4; i++) {
            gload16(Agp[i] + k0, As + i * 2048 + w * 512);
            gload16(Bgp[i] + k0, Bs + i * 2048 + w * 512);
        }
        __syncthreads();

#pragma unroll
        for (int ks = 0; ks < 4; ks++) {
            const int co = ((ks * 2 + lh) ^ sx) * 8;
            short8 af[2], bfr[2];
#pragma unroll
            for (int mt = 0; mt < 2; mt++)
                af[mt] = *reinterpret_cast<const short8*>(As + (wm + mt * 32 + l32) * 64 + co);
#pragma unroll
            for (int nt = 0; nt < 2; nt++)
                bfr[nt] = *reinterpret_cast<const short8*>(Bs + (wn + nt * 32 + l32) * 64 + co);
#pragma unroll
            for (int mt = 0; mt < 2; mt++)
#pragma unroll
                for (int nt = 0; nt < 2; nt++)
                    acc[mt][nt] = __builtin_amdgcn_mfma_f32_32x32x16_bf16(af[mt], bfr[nt], acc[mt][nt], 0, 0, 0);
        }
    }

    unsigned short* dst = (by < 6) ? Qo : (by < 12) ? Ko : Vo;
    const int bnl = (by % 6) * 128;
#pragma unroll
    for (int mt = 0; mt < 2; mt++) {
#pragma unroll
        for (int nt = 0; nt < 2; nt++) {
            int colg = bn + wn + nt * 32 + l32;
            int coll = bnl + wn + nt * 32 + l32;
            float bb = bias[colg];
#pragma unroll
            for (int rg = 0; rg < 4; rg++) {
                int rowb = bm + wm + mt * 32 + rg * 8 + lh * 4;
#pragma unroll
                for (int rr = 0; rr < 4; rr++)
                    dst[(size_t)(rowb + rr) * EMB + coll] = f2bf(acc[mt][nt][rg * 4 + rr] + bb);
            }
        }
    }
}

// ---------------- proj GEMM (64x128 tile, BK=64, 32x32x16 MFMA; grid 128x6) ----------------
__global__ __launch_bounds__(256) void gemm_proj(
    const unsigned short* __restrict__ A,
    const unsigned short* __restrict__ Bm,
    const float* __restrict__ bias,
    float* __restrict__ C) {
    __shared__ unsigned short As[64 * 64];
    __shared__ unsigned short Bs[128 * 64];
    const int K = EMB, N = EMB;

    const int t = threadIdx.x;
    const int lane = t & 63;
    const int w = t >> 6;
    const int wm = (w >> 1) * 32;
    const int wn = (w & 1) * 64;
    const int l32 = lane & 31;
    const int lh = lane >> 5;
    const int bm = blockIdx.x * 64;
    const int bn = blockIdx.y * 128;

    const unsigned short* Agp[2];
    const unsigned short* Bgp[4];
#pragma unroll
    for (int i = 0; i < 2; i++) {
        int f = i * 2048 + w * 512 + lane * 8;
        int row = f >> 6;
        int cc = (f >> 3) & 7;
        Agp[i] = A + (size_t)(bm + row) * K + ((cc ^ (row & 7)) * 8);
    }
#pragma unroll
    for (int i = 0; i < 4; i++) {
        int f = i * 2048 + w * 512 + lane * 8;
        int row = f >> 6;
        int cc = (f >> 3) & 7;
        Bgp[i] = Bm + (size_t)(bn + row) * K + ((cc ^ (row & 7)) * 8);
    }

    floatx16 acc[2];
#pragma unroll
    for (int j = 0; j < 2; j++)
#pragma unroll
        for (int r = 0; r < 16; r++) acc[j][r] = 0.0f;

    const int sx = lane & 7;
    for (int k0 = 0; k0 < K; k0 += 64) {
        __syncthreads();
#pragma unroll
        for (int i = 0; i < 2; i++) gload16(Agp[i] + k0, As + i * 2048 + w * 512);
#pragma unroll
        for (int i = 0; i < 4; i++) gload16(Bgp[i] + k0, Bs + i * 2048 + w * 512);
        __syncthreads();

#pragma unroll
        for (int ks = 0; ks < 4; ks++) {
            const int co = ((ks * 2 + lh) ^ sx) * 8;
            short8 af = *reinterpret_cast<const short8*>(As + (wm + l32) * 64 + co);
            short8 bfr[2];
#pragma unroll
            for (int nt = 0; nt < 2; nt++)
                bfr[nt] = *reinterpret_cast<const short8*>(Bs + (wn + nt * 32 + l32) * 64 + co);
#pragma unroll
            for (int nt = 0; nt < 2; nt++)
                acc[nt] = __builtin_amdgcn_mfma_f32_32x32x16_bf16(af, bfr[nt], acc[nt], 0, 0, 0);
        }
    }

#pragma unroll
    for (int nt = 0; nt < 2; nt++) {
        int col = bn + wn + nt * 32 + l32;
        float bb = bias[col];
#pragma unroll
        for (int rg = 0; rg < 4; rg++) {
            int rowb = bm + wm + rg * 8 + lh * 4;
#pragma unroll
            for (int rr = 0; rr < 4; rr++)
                C[(size_t)(rowb + rr) * N + col] = acc[nt][rg * 4 + rr] + bb;
        }
    }
}

// ---------------- V transpose with kappa key-permutation (flat head blocks) ----------------
// Vt[bh][d][blk*64 + p] = V[bh][blk*64 + kappa(p)][d],
// kappa(p) = (p & ~12) | ((p&4)<<1) | ((p&8)>>1)   (swap key-quads 1<->2 per 16)
// so the attn PV B-fragment packs linearly from sacc (reg r = j + 8*(kt2&1)).
__global__ __launch_bounds__(256) void transpose_v(const unsigned short* __restrict__ V,
                                                   unsigned short* __restrict__ Vt) {
    __shared__ unsigned short L[64 * 104];
    const int t = threadIdx.x;
    const int bh = blockIdx.x, nb = blockIdx.y;
    const unsigned short* Vg = V + (size_t)bh * HEADBLK + (size_t)nb * 64 * DH;
#pragma unroll
    for (int i = 0; i < 3; i++) {
        int f = i * 2048 + t * 8;
        int r = f / 96, c = f - r * 96;
        *reinterpret_cast<short8*>(L + r * 104 + c) = *reinterpret_cast<const short8*>(Vg + f);
    }
    __syncthreads();
    unsigned short* dst = Vt + (size_t)bh * HEADBLK;
#pragma unroll
    for (int i = 0; i < 3; i++) {
        int f = i * 2048 + t * 8;
        int d = f >> 6, c0 = f & 63;
        union { short8 s; unsigned short u[8]; } o;
#pragma unroll
        for (int j = 0; j < 8; j++) {
            int c = c0 + j;
            int key = (c & ~12) | ((c & 4) << 1) | ((c & 8) >> 1);
            o.u[j] = L[key * 104 + d];
        }
        *reinterpret_cast<short8*>(dst + d * SEQ + nb * 64 + c0) = o.s;
    }
}

// ---------------- flash attention, S^T form, 32x32x16 MFMA, dbuf LDS ----------------
// grid (64 heads, 8 qb): flat id = bh + 64*qb -> XCD = bh%8 (all q-blocks of a
// head share one XCD's L2). Block = 128 q rows, wave owns 32 q (l32 = q).
// S^T = K*Q per 64-key tile: A = K (m=key), B = Q regs (n=q), sacc[kt] col=q,
// row=key=(r&3)+8*(r>>2)+4*lh. m=0 softmax (|S|<~18 bounded): exp in place,
// row-sum = 31 adds + 1 shfl_xor(32). PV: A = kappa-permuted Vt (m=d), B = P
// packed from sacc regs r = j + 8*(kt2&1).
// Double-buffered Ks/Vs: per kb-iter = {write buf[cur]; prefetch kb+1 to regs;
// lgkmcnt(0)+s_barrier; compute buf[cur]}. One barrier/iter; raw s_barrier
// avoids vmcnt drain so the prefetch stays in flight across it.
__global__ __launch_bounds__(256, 2) void attn_kernel(
    const unsigned short* __restrict__ Q,
    const unsigned short* __restrict__ K,
    const unsigned short* __restrict__ Vt,   // per head: 96 x 1024, keys kappa-permuted per 16
    unsigned short* __restrict__ O) {
    __shared__ unsigned short Ks[2 * 64 * 104];
    __shared__ unsigned short Vs[2 * 96 * 72];
    const int KSZ = 64 * 104;   // 6656 hw per buffer
    const int VSZ = 96 * 72;    // 6912 hw per buffer

    const int t = threadIdx.x;
    const int lane = t & 63;
    const int w = t >> 6;
    const int l32 = lane & 31;
    const int lh = lane >> 5;
    const int bh = blockIdx.x, qb = blockIdx.y;

    const unsigned short* Qh = Q + (size_t)bh * HEADBLK;
    const unsigned short* Kh = K + (size_t)bh * HEADBLK;
    const unsigned short* Vth = Vt + (size_t)bh * HEADBLK;

    // Q B-fragments (32x32x16): n = l32 = q row, k = lh*8+j, ks = 0..5 chunks of 16.
    short8 qf[6];
    {
        const unsigned short* qsrc = Qh + (size_t)(qb * 128 + w * 32 + l32) * DH + lh * 8;
#pragma unroll
        for (int ks = 0; ks < 6; ks++)
            qf[ks] = *reinterpret_cast<const short8*>(qsrc + ks * 16);
    }

    const unsigned short* Kp[3];
    const unsigned short* Vp[3];
    unsigned short* KsW[3];
    unsigned short* VsW[3];
#pragma unroll
    for (int i = 0; i < 3; i++) {
        int f = i * 2048 + t * 8;
        int r = f / 96, c = f - r * 96;
        Kp[i] = Kh + f;              // + kb*6144
        KsW[i] = Ks + r * 104 + c;
        int d = f >> 6, cv = f & 63;
        Vp[i] = Vth + d * SEQ + cv;  // + kb*64
        VsW[i] = Vs + d * 72 + cv;
    }

    short8 kreg[3], vreg[3];
#pragma unroll
    for (int i = 0; i < 3; i++) {
        kreg[i] = *reinterpret_cast<const short8*>(Kp[i]);
        vreg[i] = *reinterpret_cast<const short8*>(Vp[i]);
    }

    float l_ = 0.0f;
    floatx16 acco[3];
#pragma unroll
    for (int n = 0; n < 3; n++)
#pragma unroll
        for (int r = 0; r < 16; r++) acco[n][r] = 0.0f;

    for (int kb = 0; kb < 16; kb++) {
        const int ko = (kb & 1) * KSZ;
        const int vo = (kb & 1) * VSZ;
        // write current tile into buf[kb&1] (safe: the last reads of this
        // buffer were in iter kb-2, completed before the iter kb-1 barrier)
#pragma unroll
        for (int i = 0; i < 3; i++) {
            *reinterpret_cast<short8*>(KsW[i] + ko) = kreg[i];
            *reinterpret_cast<short8*>(VsW[i] + vo) = vreg[i];
        }
        // prefetch next tile to regs BEFORE the barrier (overlaps barrier+compute)
        if (kb < 15) {
#pragma unroll
            for (int i = 0; i < 3; i++) {
                kreg[i] = *reinterpret_cast<const short8*>(Kp[i] + (kb + 1) * 6144);
                vreg[i] = *reinterpret_cast<const short8*>(Vp[i] + (kb + 1) * 64);
            }
        }
        asm volatile("s_waitcnt lgkmcnt(0)" ::: "memory");
        __builtin_amdgcn_s_barrier();

        floatx16 sacc[2];
#pragma unroll
        for (int kt = 0; kt < 2; kt++)
#pragma unroll
            for (int r = 0; r < 16; r++) sacc[kt][r] = 0.0f;

#pragma unroll
        for (int ks = 0; ks < 6; ks++) {
#pragma unroll
            for (int kt = 0; kt < 2; kt++) {
                short8 ak = *reinterpret_cast<const short8*>(
                    Ks + ko + (kt * 32 + l32) * 104 + ks * 16 + lh * 8);
                sacc[kt] = __builtin_amdgcn_mfma_f32_32x32x16_bf16(ak, qf[ks], sacc[kt], 0, 0, 0);
            }
        }

        // exp in place; row-sum (lane holds 32 keys of one q; partner lane ^32
        // holds the other 32 keys of the same q)
        float rs = 0.0f;
#pragma unroll
        for (int kt = 0; kt < 2; kt++)
#pragma unroll
            for (int r = 0; r < 16; r++) {
                float v = __expf(sacc[kt][r]);
                sacc[kt][r] = v;
                rs += v;
            }
        rs += __shfl_xor(rs, 32);
        l_ += rs;

#pragma unroll
        for (int kt2 = 0; kt2 < 4; kt2++) {
            const int kt = kt2 >> 1, ro = (kt2 & 1) * 8;
            union { short8 s8; unsigned u[4]; } bp;
#pragma unroll
            for (int p = 0; p < 4; p++)
                bp.u[p] = pk2(sacc[kt][ro + 2 * p], sacc[kt][ro + 2 * p + 1]);
#pragma unroll
            for (int n = 0; n < 3; n++) {
                short8 av = *reinterpret_cast<const short8*>(
                    Vs + vo + (n * 32 + l32) * 72 + kt2 * 16 + lh * 8);
                acco[n] = __builtin_amdgcn_mfma_f32_32x32x16_bf16(av, bp.s8, acco[n], 0, 0, 0);
            }
        }
    }

    const float inv_sqrt_e = 0.036084391824351615f;
    float invl = inv_sqrt_e / l_;
    unsigned short* dst = O + (size_t)bh * HEADBLK +
                          (size_t)(qb * 128 + w * 32 + l32) * DH + lh * 4;
#pragma unroll
    for (int n = 0; n < 3; n++) {
#pragma unroll
        for (int rg = 0; rg < 4; rg++) {
            uint2 o2;
            o2.x = pk2(acco[n][rg * 4 + 0] * invl, acco[n][rg * 4 + 1] * invl);
            o2.y = pk2(acco[n][rg * 4 + 2] * invl, acco[n][rg * 4 + 3] * invl);
            *reinterpret_cast<uint2*>(dst + n * 32 + rg * 8) = o2;
        }
    }
}

extern "C" void kernel_launch(void* const* d_in, const int* in_sizes, int n_in,
                              void* d_out, int out_size, void* d_ws, size_t ws_size,
                              hipStream_t stream) {
    const float* x = (const float*)d_in[0];
    const float* Wq = (const float*)d_in[1];
    const float* bq = (const float*)d_in[2];
    const float* Wk = (const float*)d_in[3];
    const float* bk = (const float*)d_in[4];
    const float* Wv = (const float*)d_in[5];
    const float* bv = (const float*)d_in[6];
    const float* Wp = (const float*)d_in[7];
    const float* bp = (const float*)d_in[8];
    float* out = (float*)d_out;

    char* ws = (char*)d_ws;
    size_t off = 0;
    auto alloc = [&](size_t bytes) {
        char* p = ws + off;
        off += (bytes + 255) & ~(size_t)255;
        return p;
    };
    const int nx = MROWS * EMB;
    unsigned short* xb    = (unsigned short*)alloc((size_t)nx * 2);
    unsigned short* Wqkvb = (unsigned short*)alloc((size_t)3 * NW * 2);
    unsigned short* Wpb   = (unsigned short*)alloc((size_t)NW * 2);
    float*          biasq = (float*)alloc((size_t)QKVN * 4);
    unsigned short* Qb    = (unsigned short*)alloc((size_t)nx * 2);
    unsigned short* Kb    = (unsigned short*)alloc((size_t)nx * 2);
    unsigned short* Vb    = (unsigned short*)alloc((size_t)nx * 2);
    unsigned short* Vtb   = (unsigned short*)alloc((size_t)nx * 2);
    unsigned short* Ob    = (unsigned short*)alloc((size_t)nx * 2);

    cast_all<<<8457, 256, 0, stream>>>(x, Wq, Wk, Wv, Wp, bq, bk, bv,
                                       xb, Wqkvb, Wpb, biasq);

    gemm_qkv<<<dim3(MROWS / 128, QKVN / 128), 256, 0, stream>>>(
        xb, Wqkvb, biasq, Qb, Kb, Vb);

    transpose_v<<<dim3(NBH, SEQ / 64), 256, 0, stream>>>(Vb, Vtb);

    attn_kernel<<<dim3(NBH, SEQ / 128), 256, 0, stream>>>(Qb, Kb, Vtb, Ob);

    gemm_proj<<<dim3(MROWS / 64, EMB / 128), 256, 0, stream>>>(Ob, Wpb, bp, out);
}